// Round 1
// baseline (490.763 us; speedup 1.0000x reference)
//
#include <hip/hip_runtime.h>
#include <stdint.h>

#define LOG2E 1.44269504088896340736f

typedef __attribute__((ext_vector_type(8))) __bf16 bf16x8;
typedef __attribute__((ext_vector_type(8))) short short8;
typedef __attribute__((ext_vector_type(4))) float f32x4;

static __device__ __forceinline__ unsigned short f2bf(float f) {
    union { float f; unsigned u; } v; v.f = f;
    unsigned r = v.u + 0x7fffu + ((v.u >> 16) & 1u);   // RNE
    return (unsigned short)(r >> 16);
}

// ---------------- transpose + convert: src fp32 [R][C] -> dst bf16 [C][R] ----
__global__ __launch_bounds__(256) void k_transpose_bf16(
    const float* __restrict__ src, unsigned short* __restrict__ dst, int R, int C)
{
    __shared__ float t[32][33];
    const int tx = threadIdx.x, ty = threadIdx.y;
    const int c0 = blockIdx.x * 32, r0 = blockIdx.y * 32;
#pragma unroll
    for (int j = 0; j < 4; ++j)
        t[ty + j*8][tx] = src[(size_t)(r0 + ty + j*8) * C + (c0 + tx)];
    __syncthreads();
#pragma unroll
    for (int j = 0; j < 4; ++j)
        dst[(size_t)(c0 + ty + j*8) * R + (r0 + tx)] = f2bf(t[tx][ty + j*8]);
}

// ---------------- GEMM: A[M,1024] @ Bt[N,1024]^T, 128x128 tile, BK=32 --------
// MODE 0: A fp32 (x), epilogue scatters Q(scaled 1/8)/K -> [head][s][hd] bf16,
//         V -> [head][hd][s] bf16 (transposed), bias fused.
// MODE 1: A bf16 (attn out), epilogue bias + fp32 store to Co.
template <int NBN, int MODE>
__global__ __launch_bounds__(256) void k_gemm_bt(
    const void* __restrict__ Ap, const unsigned short* __restrict__ Bt,
    const float* __restrict__ bias,
    unsigned short* __restrict__ Qo, unsigned short* __restrict__ Ko,
    unsigned short* __restrict__ Vo, float* __restrict__ Co)
{
    constexpr int K = 1024;
    constexpr int NN = NBN * 128;
    __shared__ __align__(16) short As[128 * 32];
    __shared__ __align__(16) short Bs[128 * 32];

    const int tid = threadIdx.x;
    const int w = tid >> 6, lane = tid & 63;
    const int lo16 = lane & 15, kg = lane >> 4;
    const int bm = blockIdx.x / NBN, bn = blockIdx.x % NBN;
    const int wm = w >> 1, wn = w & 1;

    f32x4 acc[4][4] = {};

    const int r0 = tid >> 2;   // staging row (chunk i adds 64)
    const int j0 = tid & 3;    // 16B chunk within 64B row

    for (int kt = 0; kt < K / 32; ++kt) {
        short8 ra[2], rbv[2];
#pragma unroll
        for (int i = 0; i < 2; ++i) {
            const int row = i * 64 + r0;
            if constexpr (MODE == 0) {
                const float* ap = (const float*)Ap + (size_t)(bm*128 + row) * K + kt*32 + j0*8;
                const float4 f0 = *(const float4*)ap;
                const float4 f1 = *(const float4*)(ap + 4);
                short8 v;
                v[0]=(short)f2bf(f0.x); v[1]=(short)f2bf(f0.y); v[2]=(short)f2bf(f0.z); v[3]=(short)f2bf(f0.w);
                v[4]=(short)f2bf(f1.x); v[5]=(short)f2bf(f1.y); v[6]=(short)f2bf(f1.z); v[7]=(short)f2bf(f1.w);
                ra[i] = v;
            } else {
                ra[i] = *(const short8*)((const unsigned short*)Ap + (size_t)(bm*128 + row) * K + kt*32 + j0*8);
            }
            rbv[i] = *(const short8*)(Bt + (size_t)(bn*128 + row) * K + kt*32 + j0*8);
        }
        __syncthreads();   // previous tile's compute done
#pragma unroll
        for (int i = 0; i < 2; ++i) {
            const int row = i * 64 + r0;
            *(short8*)&As[row * 32 + j0 * 8] = ra[i];
            *(short8*)&Bs[row * 32 + j0 * 8] = rbv[i];
        }
        __syncthreads();   // tile staged

        bf16x8 af[4], bff[4];
#pragma unroll
        for (int rb = 0; rb < 4; ++rb)
            af[rb] = *(const bf16x8*)&As[(wm*64 + rb*16 + lo16) * 32 + kg*8];
#pragma unroll
        for (int cb = 0; cb < 4; ++cb)
            bff[cb] = *(const bf16x8*)&Bs[(wn*64 + cb*16 + lo16) * 32 + kg*8];
#pragma unroll
        for (int rb = 0; rb < 4; ++rb)
#pragma unroll
            for (int cb = 0; cb < 4; ++cb)
                acc[rb][cb] = __builtin_amdgcn_mfma_f32_16x16x32_bf16(af[rb], bff[cb], acc[rb][cb], 0, 0, 0);
    }

    // epilogue: C/D layout col=lane&15, row=(lane>>4)*4+reg  [m89]
#pragma unroll
    for (int rb = 0; rb < 4; ++rb) {
        const int m0 = bm*128 + wm*64 + rb*16 + kg*4;
#pragma unroll
        for (int cb = 0; cb < 4; ++cb) {
            const int n = bn*128 + wn*64 + cb*16 + lo16;
            const float bv = bias[n];
            if constexpr (MODE == 0) {
                const int which = n >> 10;
                const int h = (n >> 6) & 15;
                const int hd = n & 63;
                if (which == 2) {
                    // V transposed: [head][hd][s]; 4 regs = 4 consecutive s -> 8B store
                    const int b = m0 >> 11, s0 = m0 & 2047;
                    const int head = b*16 + h;
                    unsigned long long pv = 0;
#pragma unroll
                    for (int r = 0; r < 4; ++r)
                        pv |= (unsigned long long)f2bf(acc[rb][cb][r] + bv) << (16*r);
                    *(unsigned long long*)(Vo + ((size_t)head*64 + hd)*2048 + s0) = pv;
                } else {
                    unsigned short* P = (which == 0) ? Qo : Ko;
                    const float scq = (which == 0) ? 0.125f : 1.0f;  // fold 1/sqrt(HD) into Q
#pragma unroll
                    for (int r = 0; r < 4; ++r) {
                        const int m = m0 + r;
                        const int b = m >> 11, s = m & 2047;
                        P[((size_t)(b*16 + h)*2048 + s)*64 + hd] = f2bf((acc[rb][cb][r] + bv) * scq);
                    }
                }
            } else {
                (void)Qo; (void)Ko; (void)Vo;
#pragma unroll
                for (int r = 0; r < 4; ++r)
                    Co[(size_t)(m0 + r) * NN + n] = acc[rb][cb][r] + bv;
            }
        }
    }
}

// ---------------- flash attention: per block = (head, 128-row Q tile) --------
__global__ __launch_bounds__(256) void k_attn(
    const unsigned short* __restrict__ Qg, const unsigned short* __restrict__ Kg,
    const unsigned short* __restrict__ Vtg, unsigned short* __restrict__ Og)
{
    __shared__ __align__(16) short Qs[128 * 64];   // swizzled rows (128B)
    __shared__ __align__(16) short Ks[64 * 64];
    __shared__ __align__(16) short Vs[64 * 64];    // V^T tile: row=hd, col=s
    __shared__ __align__(16) short Ps[4][32 * 64]; // per-wave P

    const int tid = threadIdx.x;
    const int w = tid >> 6, lane = tid & 63;
    const int lo16 = lane & 15, kg = lane >> 4;
    const int head = blockIdx.x >> 4, qt = blockIdx.x & 15;
    const size_t hoff = (size_t)head * (2048 * 64);

    // stage Q tile [128][64] with 16B-block XOR swizzle (j ^= row&7)
#pragma unroll
    for (int i = 0; i < 4; ++i) {
        const int c = i*256 + tid;
        const int row = c >> 3, j = c & 7;
        const short8 v = *(const short8*)(Qg + hoff + (size_t)(qt*128 + row)*64 + j*8);
        *(short8*)&Qs[row*64 + (j ^ (row & 7))*8] = v;
    }
    __syncthreads();

    bf16x8 aq[2][2];   // [rowblock][kstep] held for whole kernel
#pragma unroll
    for (int rb = 0; rb < 2; ++rb)
#pragma unroll
        for (int ks = 0; ks < 2; ++ks) {
            const int q = w*32 + rb*16 + lo16;
            const int blk = (ks*4 + kg) ^ (q & 7);
            aq[rb][ks] = *(const bf16x8*)&Qs[q*64 + blk*8];
        }

    float m_run[2][4], l_run[2][4];
#pragma unroll
    for (int rb = 0; rb < 2; ++rb)
#pragma unroll
        for (int r = 0; r < 4; ++r) { m_run[rb][r] = -1e30f; l_run[rb][r] = 0.f; }
    f32x4 acc_o[2][4] = {};

    short* Pw = Ps[w];

    for (int kv0 = 0; kv0 < 2048; kv0 += 64) {
        short8 rk[2], rv[2];
#pragma unroll
        for (int i = 0; i < 2; ++i) {
            const int c = i*256 + tid;
            const int row = c >> 3, j = c & 7;
            rk[i] = *(const short8*)(Kg  + hoff + (size_t)(kv0 + row)*64 + j*8);
            rv[i] = *(const short8*)(Vtg + hoff + (size_t)row*2048 + kv0 + j*8);
        }
        __syncthreads();   // all waves done with previous K/V tile
#pragma unroll
        for (int i = 0; i < 2; ++i) {
            const int c = i*256 + tid;
            const int row = c >> 3, j = c & 7;
            const int eo = row*64 + (j ^ (row & 7))*8;
            *(short8*)&Ks[eo] = rk[i];
            *(short8*)&Vs[eo] = rv[i];
        }
        __syncthreads();   // staged

        // S = Q K^T (scale pre-folded into Q)
        f32x4 sc[2][4] = {};
#pragma unroll
        for (int ks = 0; ks < 2; ++ks) {
            bf16x8 bk[4];
#pragma unroll
            for (int cb = 0; cb < 4; ++cb) {
                const int kv = cb*16 + lo16;
                const int blk = (ks*4 + kg) ^ (kv & 7);
                bk[cb] = *(const bf16x8*)&Ks[kv*64 + blk*8];
            }
#pragma unroll
            for (int rb = 0; rb < 2; ++rb)
#pragma unroll
                for (int cb = 0; cb < 4; ++cb)
                    sc[rb][cb] = __builtin_amdgcn_mfma_f32_16x16x32_bf16(aq[rb][ks], bk[cb], sc[rb][cb], 0, 0, 0);
        }

        // online softmax (rows live on 16-lane groups; shfl_xor 1..8 stays in-group)
#pragma unroll
        for (int rb = 0; rb < 2; ++rb) {
#pragma unroll
            for (int r = 0; r < 4; ++r) {
                float t = fmaxf(fmaxf(sc[rb][0][r], sc[rb][1][r]),
                                fmaxf(sc[rb][2][r], sc[rb][3][r]));
                t = fmaxf(t, __shfl_xor(t, 1));
                t = fmaxf(t, __shfl_xor(t, 2));
                t = fmaxf(t, __shfl_xor(t, 4));
                t = fmaxf(t, __shfl_xor(t, 8));
                const float mo = m_run[rb][r];
                const float mn = fmaxf(mo, t);
                const float fac = exp2f((mo - mn) * LOG2E);
                m_run[rb][r] = mn;
                float sum = 0.f;
#pragma unroll
                for (int cb = 0; cb < 4; ++cb) {
                    const float p = exp2f((sc[rb][cb][r] - mn) * LOG2E);
                    sc[rb][cb][r] = p;
                    sum += p;
                }
                sum += __shfl_xor(sum, 1);
                sum += __shfl_xor(sum, 2);
                sum += __shfl_xor(sum, 4);
                sum += __shfl_xor(sum, 8);
                l_run[rb][r] = l_run[rb][r] * fac + sum;
#pragma unroll
                for (int hb = 0; hb < 4; ++hb) acc_o[rb][hb][r] *= fac;
            }
        }

        // P -> bf16 -> wave-private LDS (swizzled rows)
#pragma unroll
        for (int rb = 0; rb < 2; ++rb)
#pragma unroll
            for (int cb = 0; cb < 4; ++cb)
#pragma unroll
                for (int r = 0; r < 4; ++r) {
                    const int q = rb*16 + kg*4 + r;
                    const int kv = cb*16 + lo16;
                    const int bo = q*128 + ((kv*2) ^ ((q & 7) << 4));
                    Pw[bo >> 1] = (short)f2bf(sc[rb][cb][r]);
                }

        // O += P V   (A from Ps, B from Vs=V^T; compiler orders ds ops)
#pragma unroll
        for (int ks = 0; ks < 2; ++ks) {
            bf16x8 ap[2], bvv[4];
#pragma unroll
            for (int rb = 0; rb < 2; ++rb) {
                const int q = rb*16 + lo16;
                const int blk = (ks*4 + kg) ^ (q & 7);
                ap[rb] = *(const bf16x8*)&Pw[q*64 + blk*8];
            }
#pragma unroll
            for (int hb = 0; hb < 4; ++hb) {
                const int hd = hb*16 + lo16;
                const int blk = (ks*4 + kg) ^ (hd & 7);
                bvv[hb] = *(const bf16x8*)&Vs[hd*64 + blk*8];
            }
#pragma unroll
            for (int rb = 0; rb < 2; ++rb)
#pragma unroll
                for (int hb = 0; hb < 4; ++hb)
                    acc_o[rb][hb] = __builtin_amdgcn_mfma_f32_16x16x32_bf16(ap[rb], bvv[hb], acc_o[rb][hb], 0, 0, 0);
        }
    }

    // epilogue: O = acc / l -> bf16 [b][s][h*64+hd] (row-major A for out-proj)
    const int b = head >> 4, h = head & 15;
#pragma unroll
    for (int rb = 0; rb < 2; ++rb)
#pragma unroll
        for (int r = 0; r < 4; ++r) {
            const float inv = 1.0f / l_run[rb][r];
            const int s = qt*128 + w*32 + rb*16 + kg*4 + r;
#pragma unroll
            for (int hb = 0; hb < 4; ++hb) {
                const int hd = hb*16 + lo16;
                Og[(size_t)(b*2048 + s)*1024 + h*64 + hd] = f2bf(acc_o[rb][hb][r] * inv);
            }
        }
}

// ---------------------------------------------------------------------------
extern "C" void kernel_launch(void* const* d_in, const int* in_sizes, int n_in,
                              void* d_out, int out_size, void* d_ws, size_t ws_size,
                              hipStream_t stream)
{
    const float* x      = (const float*)d_in[0];
    const float* w_qkv  = (const float*)d_in[1];
    const float* b_qkv  = (const float*)d_in[2];
    const float* w_out  = (const float*)d_in[3];
    const float* b_out  = (const float*)d_in[4];
    float* out = (float*)d_out;

    char* ws = (char*)d_ws;
    unsigned short* wqkv_t = (unsigned short*)(ws);              // 3072x1024 bf16 = 6291456 B
    unsigned short* wout_t = (unsigned short*)(ws +  6291456);   // 1024x1024 bf16 = 2097152 B
    unsigned short* Qb     = (unsigned short*)(ws +  8388608);   // [64][2048][64] bf16 = 16 MiB
    unsigned short* Kb     = (unsigned short*)(ws + 25165824);   // [64][2048][64] bf16
    unsigned short* Vb     = (unsigned short*)(ws + 41943040);   // [64][64][2048] bf16 (V^T)
    unsigned short* AO     = (unsigned short*)(ws + 58720256);   // [8192][1024] bf16
    // total ws use: 75,497,472 B

    // weights -> bf16, transposed to [N][K] for K-contiguous B-fragments
    k_transpose_bf16<<<dim3(96, 32), dim3(32, 8), 0, stream>>>(w_qkv, wqkv_t, 1024, 3072);
    k_transpose_bf16<<<dim3(32, 32), dim3(32, 8), 0, stream>>>(w_out, wout_t, 1024, 1024);
    // QKV projection + scatter (Q pre-scaled by 1/8, V transposed)
    k_gemm_bt<24, 0><<<64 * 24, 256, 0, stream>>>(x, wqkv_t, b_qkv, Qb, Kb, Vb, nullptr);
    // fused flash attention
    k_attn<<<64 * 16, 256, 0, stream>>>(Qb, Kb, Vb, AO);
    // output projection (fp32 out + bias)
    k_gemm_bt<8, 1><<<64 * 8, 256, 0, stream>>>(AO, wout_t, b_out, nullptr, nullptr, nullptr, out);
}